// Round 13
// baseline (65.623 us; speedup 1.0000x reference)
//
#include <hip/hip_runtime.h>

#define LN 63
#define BATCHN 16384

typedef __attribute__((ext_vector_type(8))) short bf16x8;   // 8 bf16 in 4 VGPRs
typedef __attribute__((ext_vector_type(4))) float f32x4;

__device__ __forceinline__ float fast_exp(float v) {
    return __builtin_amdgcn_exp2f(v * 1.4426950408889634f);
}
__device__ __forceinline__ float fast_tanh(float v) {
    float e = __builtin_amdgcn_exp2f(v * 2.8853900817779268f); // e^{2v}
    return 1.0f - 2.0f * __builtin_amdgcn_rcpf(e + 1.0f);
}
__device__ __forceinline__ short f2bf(float f) {
    __bf16 h = (__bf16)f;
    return __builtin_bit_cast(short, h);
}
__device__ __forceinline__ unsigned int pk2(float a, float b) {
    return (unsigned int)(unsigned short)f2bf(a) |
           ((unsigned int)(unsigned short)f2bf(b) << 16);
}

// kappa j-index for W2/W3 fragment element e (derived from R6's verified LDS
// reads): e<4 -> 32s+4g+e ; e>=4 -> 32s+16+4g+(e-4).
__device__ __forceinline__ int kappa_j(int s, int g, int e) {
    return (e < 4) ? (32 * s + 4 * g + e) : (32 * s + 16 + 4 * g + e - 4);
}

// Combined prep: blocks 0..62 write per-lane fragment-ordered bf16 weights
// into Afrag[l] (18432 B per l); blocks 63.. convert x -> xbf.  (R9-verified)
__global__ __launch_bounds__(256) void prep_kernel(
    const float* __restrict__ x,
    const float* __restrict__ W1, const float* __restrict__ b1,
    const float* __restrict__ W2, const float* __restrict__ W3,
    unsigned short* __restrict__ Afrag,
    unsigned short* __restrict__ xbf)
{
    const int t = threadIdx.x;
    const int b = blockIdx.x;
    if (b >= LN) {
        const int i = ((b - LN) * 256 + t) * 4;
        const float4 v = *reinterpret_cast<const float4*>(x + i);
        ushort4 o;
        o.x = (unsigned short)f2bf(v.x);
        o.y = (unsigned short)f2bf(v.y);
        o.z = (unsigned short)f2bf(v.z);
        o.w = (unsigned short)f2bf(v.w);
        *reinterpret_cast<ushort4*>(xbf + i) = o;
        return;
    }
    const int l = b;
    unsigned short* Af = Afrag + (size_t)l * 9216;

    // A1: 512 items (s,tt,lane), 2 per thread
    #pragma unroll
    for (int it = 0; it < 2; ++it) {
        const int item = t + it * 256;
        const int s = item >> 8, tt = (item >> 6) & 3, lane = item & 63;
        const int g = lane >> 4, mcol = lane & 15, h = 16 * tt + mcol;
        unsigned pk[4];
        #pragma unroll
        for (int ep = 0; ep < 4; ++ep) {
            float v[2];
            #pragma unroll
            for (int k = 0; k < 2; ++k) {
                const int e = 2 * ep + k;
                const int j = 32 * s + 8 * g + e;
                float val;
                if (j == 63)      val = b1[l * 64 + h];
                else if (j <= l)  val = W1[(l * LN + j) * 64 + h];
                else              val = 0.0f;
                v[k] = val;
            }
            pk[ep] = pk2(v[0], v[1]);
        }
        *reinterpret_cast<uint4*>(Af + ((size_t)item) * 8) =
            uint4{pk[0], pk[1], pk[2], pk[3]};
    }
    // A2: 512 items
    #pragma unroll
    for (int it = 0; it < 2; ++it) {
        const int item = t + it * 256;
        const int s = item >> 8, tt = (item >> 6) & 3, lane = item & 63;
        const int g = lane >> 4, mcol = lane & 15, h = 16 * tt + mcol;
        unsigned pk[4];
        #pragma unroll
        for (int ep = 0; ep < 4; ++ep) {
            float v[2];
            #pragma unroll
            for (int k = 0; k < 2; ++k) {
                const int e = 2 * ep + k;
                v[k] = W2[(l * 64 + kappa_j(s, g, e)) * 64 + h];
            }
            pk[ep] = pk2(v[0], v[1]);
        }
        *reinterpret_cast<uint4*>(Af + 4096 + ((size_t)item) * 8) =
            uint4{pk[0], pk[1], pk[2], pk[3]};
    }
    // A3: 128 items (s,lane)
    if (t < 128) {
        const int s = t >> 6, lane = t & 63;
        const int g = lane >> 4, mcol = lane & 15;
        unsigned pk[4] = {0u, 0u, 0u, 0u};
        if (mcol < 2) {
            #pragma unroll
            for (int ep = 0; ep < 4; ++ep) {
                float v[2];
                #pragma unroll
                for (int k = 0; k < 2; ++k) {
                    const int e = 2 * ep + k;
                    v[k] = W3[(l * 64 + kappa_j(s, g, e)) * 2 + mcol];
                }
                pk[ep] = pk2(v[0], v[1]);
            }
        }
        *reinterpret_cast<uint4*>(Af + 8192 + ((size_t)t) * 8) =
            uint4{pk[0], pk[1], pk[2], pk[3]};
    }
}

// One chain's compute, parameterized by registers. Macro-free: inline fn.
// (All indices static; callers pass named values -> no scratch.)
struct ChainOut { float mu, al; };

// Block = one l (0..62) x 1024 batch rows. Grid 63*16 = 1008. No LDS.
// R12: dependency-latency attack (R9-R11 showed all pipes <=56% at 2 waves).
// (a) DUAL-CHAIN: each iteration computes TWO row-groups A/B sharing the same
//     w1f/w2f/w3f operands, interleaved in source -> chain B fills chain A's
//     MFMA/tanh latency. (b) xf software pipeline: iteration it issues loads
//     for it+1; L2 latency (~300cy) hidden under compute.
// Math identical to R9/R11 (verified absmax 0.0625).
template<int XBF>
__global__ __launch_bounds__(256, 2) void maf_main_kernel(
    const float* __restrict__ x,
    const unsigned short* __restrict__ xbf,
    const unsigned short* __restrict__ Afrag,
    const float* __restrict__ b2,
    const float* __restrict__ b3,
    float* __restrict__ zT,   // ws: [63][BATCH] row cr=62-l (z col l+1 reversed)
    float* __restrict__ aT)   // ws: [63][BATCH] alpha col l+1
{
    const int t = threadIdx.x;
    const int bid = blockIdx.x;
    const int l = bid % LN;                 // block-uniform
    const int rowBase = (bid / LN) * 1024;

    const int lane = t & 63;
    const int w = t >> 6;
    const int g = lane >> 4;
    const int mcol = lane & 15;

    // ---------------- persistent A-fragments: W2, W3, bias2 ----------------
    const unsigned short* Af = Afrag + (size_t)l * 9216;
    bf16x8 w2f[2][4], w3f[2];
    #pragma unroll
    for (int s = 0; s < 2; ++s) {
        #pragma unroll
        for (int tt = 0; tt < 4; ++tt)
            w2f[s][tt] = *reinterpret_cast<const bf16x8*>(Af + 4096 + ((s * 4 + tt) * 64 + lane) * 8);
        w3f[s] = *reinterpret_cast<const bf16x8*>(Af + 8192 + (s * 64 + lane) * 8);
    }
    f32x4 bias2[4];
    #pragma unroll
    for (int tt = 0; tt < 4; ++tt) {
        const float4 v2 = *reinterpret_cast<const float4*>(&b2[l * 64 + 16 * tt + 4 * g]);
        bias2[tt] = f32x4{v2.x, v2.y, v2.z, v2.w};
    }
    const float b30 = b3[l * 2 + 0];
    const float b31 = b3[l * 2 + 1];
    const short one_bf = (short)0x3F80;   // bf16(1.0)

    const int rowW = rowBase + w * 256 + mcol;   // row for grp 0 of this wave
    const unsigned short* xrow = xbf + (size_t)rowW * 64 + 8 * g;

    // xf loader for row-group k (0..15): rows rowW + 16k
    auto ldxf = [&](int k, bf16x8& f0, bf16x8& f1) {
        const unsigned short* p = xrow + (size_t)(16 * k) * 64;
        f0 = *reinterpret_cast<const bf16x8*>(p);
        f1 = *reinterpret_cast<const bf16x8*>(p + 32);
        if (g == 3) f1[7] = one_bf;   // b1 k-slot 63 pairs with 1.0
    };

    // prologue: prefetch groups 0 and 1
    bf16x8 xa0, xa1, xb0, xb1, na0, na1, nb0, nb1;
    ldxf(0, xa0, xa1);
    ldxf(1, xb0, xb1);

    // ---------------- 8 iterations x 2 row-groups ----------------
    #pragma unroll 1
    for (int it = 0; it < 8; ++it) {
        // prefetch next pair (clamped at tail; redundant loads are L1 hits)
        const int nk = (it < 7) ? (2 * it + 2) : 14;
        ldxf(nk, na0, na1);
        ldxf(nk + 1, nb0, nb1);

        // w1f: 8 x 16B, L1-resident (same addr every iteration)
        bf16x8 w1f[2][4];
        #pragma unroll
        for (int s = 0; s < 2; ++s)
            #pragma unroll
            for (int tt = 0; tt < 4; ++tt)
                w1f[s][tt] = *reinterpret_cast<const bf16x8*>(Af + ((s * 4 + tt) * 64 + lane) * 8);

        // ---- layer 1, chains A and B interleaved (shared w1f) ----
        f32x4 c1a[4], c1b[4];
        #pragma unroll
        for (int tt = 0; tt < 4; ++tt) {
            c1a[tt] = f32x4{0.0f, 0.0f, 0.0f, 0.0f};
            c1b[tt] = f32x4{0.0f, 0.0f, 0.0f, 0.0f};
        }
        #pragma unroll
        for (int tt = 0; tt < 4; ++tt) {
            c1a[tt] = __builtin_amdgcn_mfma_f32_16x16x32_bf16(w1f[0][tt], xa0, c1a[tt], 0, 0, 0);
            c1b[tt] = __builtin_amdgcn_mfma_f32_16x16x32_bf16(w1f[0][tt], xb0, c1b[tt], 0, 0, 0);
        }
        #pragma unroll
        for (int tt = 0; tt < 4; ++tt) {
            c1a[tt] = __builtin_amdgcn_mfma_f32_16x16x32_bf16(w1f[1][tt], xa1, c1a[tt], 0, 0, 0);
            c1b[tt] = __builtin_amdgcn_mfma_f32_16x16x32_bf16(w1f[1][tt], xb1, c1b[tt], 0, 0, 0);
        }

        // ---- tanh + pack, interleaved ----
        bf16x8 pfa[2], pfb[2];
        #pragma unroll
        for (int s = 0; s < 2; ++s) {
            bf16x8 fa, fb;
            #pragma unroll
            for (int q = 0; q < 4; ++q) {
                fa[q]     = f2bf(fast_tanh(c1a[2 * s][q]));
                fb[q]     = f2bf(fast_tanh(c1b[2 * s][q]));
                fa[4 + q] = f2bf(fast_tanh(c1a[2 * s + 1][q]));
                fb[4 + q] = f2bf(fast_tanh(c1b[2 * s + 1][q]));
            }
            pfa[s] = fa;
            pfb[s] = fb;
        }

        // ---- layer 2, interleaved (shared w2f) ----
        f32x4 c2a[4], c2b[4];
        #pragma unroll
        for (int tt = 0; tt < 4; ++tt) { c2a[tt] = bias2[tt]; c2b[tt] = bias2[tt]; }
        #pragma unroll
        for (int s = 0; s < 2; ++s)
            #pragma unroll
            for (int tt = 0; tt < 4; ++tt) {
                c2a[tt] = __builtin_amdgcn_mfma_f32_16x16x32_bf16(w2f[s][tt], pfa[s], c2a[tt], 0, 0, 0);
                c2b[tt] = __builtin_amdgcn_mfma_f32_16x16x32_bf16(w2f[s][tt], pfb[s], c2b[tt], 0, 0, 0);
            }

        bf16x8 qfa[2], qfb[2];
        #pragma unroll
        for (int s = 0; s < 2; ++s) {
            bf16x8 fa, fb;
            #pragma unroll
            for (int q = 0; q < 4; ++q) {
                fa[q]     = f2bf(fast_tanh(c2a[2 * s][q]));
                fb[q]     = f2bf(fast_tanh(c2b[2 * s][q]));
                fa[4 + q] = f2bf(fast_tanh(c2a[2 * s + 1][q]));
                fb[4 + q] = f2bf(fast_tanh(c2b[2 * s + 1][q]));
            }
            qfa[s] = fa;
            qfb[s] = fb;
        }

        // ---- layer 3, interleaved (shared w3f) ----
        f32x4 c3a = {0.0f, 0.0f, 0.0f, 0.0f};
        f32x4 c3b = {0.0f, 0.0f, 0.0f, 0.0f};
        c3a = __builtin_amdgcn_mfma_f32_16x16x32_bf16(w3f[0], qfa[0], c3a, 0, 0, 0);
        c3b = __builtin_amdgcn_mfma_f32_16x16x32_bf16(w3f[0], qfb[0], c3b, 0, 0, 0);
        c3a = __builtin_amdgcn_mfma_f32_16x16x32_bf16(w3f[1], qfa[1], c3a, 0, 0, 0);
        c3b = __builtin_amdgcn_mfma_f32_16x16x32_bf16(w3f[1], qfb[1], c3b, 0, 0, 0);

        if (g == 0) {
            const int rowA = rowW + 32 * it;
            const int rowB = rowA + 16;
            const float muA = c3a[0] + b30, alA = c3a[1] + b31;
            const float muB = c3b[0] + b30, alB = c3b[1] + b31;
            const float xnA = x[(size_t)rowA * 64 + l + 1];
            const float xnB = x[(size_t)rowB * 64 + l + 1];
            zT[(62 - l) * BATCHN + rowA] = (xnA - muA) * fast_exp(-alA);
            zT[(62 - l) * BATCHN + rowB] = (xnB - muB) * fast_exp(-alB);
            aT[l * BATCHN + rowA] = alA;
            aT[l * BATCHN + rowB] = alB;
        }

        // rotate prefetch
        xa0 = na0; xa1 = na1; xb0 = nb0; xb1 = nb1;
    }
}

// 256 blocks x 64 rows: log_det + z col 0 + LDS transpose -> coalesced z_out.
__global__ __launch_bounds__(256) void maf_finish_kernel(
    const float* __restrict__ x,
    const float* __restrict__ ip,
    const float* __restrict__ zT,
    const float* __restrict__ aT,
    float* __restrict__ z_out,
    float* __restrict__ ld_out)
{
    __shared__ float tile[64][65];

    const int t = threadIdx.x;
    const int rb = blockIdx.x * 64;
    const float mu0 = ip[0];
    const float a0  = ip[1];
    const float e0  = fast_exp(-a0);

    // log_det: 4 lanes per row, shfl reduce
    {
        const int r = t >> 2, c = t & 3;
        const int row = rb + r;
        float s = 0.0f;
        for (int i = c; i < LN; i += 4) s += aT[(size_t)i * BATCHN + row];
        s += __shfl_xor(s, 1, 64);
        s += __shfl_xor(s, 2, 64);
        if (c == 0) ld_out[row] = -(s + a0);
    }

    // transpose 64 rows x 64 cols
    const int r = t & 63, cq = t >> 6;
    #pragma unroll
    for (int k = 0; k < 16; ++k) {
        const int c = cq * 16 + k;
        float v;
        if (c < 63) v = zT[(size_t)c * BATCHN + rb + r];
        else        v = (x[(size_t)(rb + r) * 64] - mu0) * e0;  // z col 0 -> cr 63
        tile[c][r] = v;
    }
    __syncthreads();
    #pragma unroll
    for (int i = 0; i < 16; ++i) {
        const int rr = cq * 16 + i;
        z_out[(size_t)(rb + rr) * 64 + r] = tile[r][rr];
    }
}

extern "C" void kernel_launch(void* const* d_in, const int* in_sizes, int n_in,
                              void* d_out, int out_size, void* d_ws, size_t ws_size,
                              hipStream_t stream) {
    const float* x  = (const float*)d_in[0];
    const float* ip = (const float*)d_in[1];
    const float* W1 = (const float*)d_in[2];
    const float* b1 = (const float*)d_in[3];
    const float* W2 = (const float*)d_in[4];
    const float* b2 = (const float*)d_in[5];
    const float* W3 = (const float*)d_in[6];
    const float* b3 = (const float*)d_in[7];

    float* z_out  = (float*)d_out;                     // [16384][64] (reversed cols)
    float* ld_out = z_out + (size_t)BATCHN * 64;       // [16384]

    // ws layout: Afrag [63*9216 u16 = 1.16MB] | zT 4.13MB | aT 4.13MB | xbf 2MB
    unsigned short* Afrag = (unsigned short*)d_ws;
    float* zT = (float*)((char*)d_ws + (size_t)LN * 9216 * 2);
    float* aT = zT + (size_t)LN * BATCHN;
    unsigned short* xbf = (unsigned short*)(aT + (size_t)LN * BATCHN);

    prep_kernel<<<dim3(LN + BATCHN * 64 / 1024), dim3(256), 0, stream>>>(
        x, W1, b1, W2, W3, Afrag, xbf);
    maf_main_kernel<1><<<dim3(LN * 16), dim3(256), 0, stream>>>(
        x, xbf, Afrag, b2, b3, zT, aT);
    maf_finish_kernel<<<dim3(BATCHN / 64), dim3(256), 0, stream>>>(
        x, ip, zT, aT, z_out, ld_out);
}